// Round 13
// baseline (1564.970 us; speedup 1.0000x reference)
//
#include <hip/hip_runtime.h>
#include <math.h>

__device__ __forceinline__ float fma4(float4 w, float4 a, float acc) {
  return fmaf(w.w, a.w, fmaf(w.z, a.z, fmaf(w.y, a.y, fmaf(w.x, a.x, acc))));
}

// ==================== shared device helpers (1 wave, 16 rows, 8 cols/lane) ====================
// Lane group gr8 = (l>>5)*8 owns rows gr8..gr8+7; lane owns cols c0..c0+7 (c0=(l&31)*8).
// A[16][256] = 16 KB. LN scratch P aliased into A (rows 0..2): row stride 36, slots 0..31
// partials + slot 32 stat. Safe because every P write happens after the A tile has been
// fully consumed into registers (single in-order wave) and before storeA rewrites A.

// 256-FMA quad step: 8 rows x 8 cols, k-quad kq (A-read is 2-address broadcast).
__device__ __forceinline__ void quadf(const float (*A)[256], int kq, const float4* wbuf,
                                      float* acc, int gr8) {
  float4 a_[8];
  #pragma unroll
  for (int i = 0; i < 8; ++i) a_[i] = *(const float4*)&A[gr8 + i][kq * 4];
  #pragma unroll
  for (int kk = 0; kk < 4; ++kk) {
    const float4 wlo = wbuf[kk * 2], whi = wbuf[kk * 2 + 1];
    #pragma unroll
    for (int i = 0; i < 8; ++i) {
      const float av = kk == 0 ? a_[i].x : kk == 1 ? a_[i].y : kk == 2 ? a_[i].z : a_[i].w;
      acc[i * 8 + 0] = fmaf(av, wlo.x, acc[i * 8 + 0]);
      acc[i * 8 + 1] = fmaf(av, wlo.y, acc[i * 8 + 1]);
      acc[i * 8 + 2] = fmaf(av, wlo.z, acc[i * 8 + 2]);
      acc[i * 8 + 3] = fmaf(av, wlo.w, acc[i * 8 + 3]);
      acc[i * 8 + 4] = fmaf(av, whi.x, acc[i * 8 + 4]);
      acc[i * 8 + 5] = fmaf(av, whi.y, acc[i * 8 + 5]);
      acc[i * 8 + 6] = fmaf(av, whi.z, acc[i * 8 + 6]);
      acc[i * 8 + 7] = fmaf(av, whi.w, acc[i * 8 + 7]);
    }
  }
}

// GEMM: acc[8r x 8c] = A[16][4*NKQ] @ WT, W double-buffered (identical order to r8).
template <int NKQ>
__device__ __forceinline__ void gemm256(const float (*A)[256], const float* __restrict__ WT,
                                        float* acc, int gr8, int c0) {
  #pragma unroll
  for (int i = 0; i < 64; ++i) acc[i] = 0.f;
  float4 wA[8], wB[8];
  #pragma unroll
  for (int kk = 0; kk < 4; ++kk) {
    wA[kk * 2]     = *(const float4*)&WT[(size_t)kk * 256 + c0];
    wA[kk * 2 + 1] = *(const float4*)&WT[(size_t)kk * 256 + c0 + 4];
  }
  #pragma unroll 1
  for (int kq = 0; kq < NKQ; kq += 2) {
    #pragma unroll
    for (int kk = 0; kk < 4; ++kk) {
      wB[kk * 2]     = *(const float4*)&WT[(size_t)((kq + 1) * 4 + kk) * 256 + c0];
      wB[kk * 2 + 1] = *(const float4*)&WT[(size_t)((kq + 1) * 4 + kk) * 256 + c0 + 4];
    }
    quadf(A, kq, wA, acc, gr8);
    if (kq + 2 < NKQ) {
      #pragma unroll
      for (int kk = 0; kk < 4; ++kk) {
        wA[kk * 2]     = *(const float4*)&WT[(size_t)((kq + 2) * 4 + kk) * 256 + c0];
        wA[kk * 2 + 1] = *(const float4*)&WT[(size_t)((kq + 2) * 4 + kk) * 256 + c0 + 4];
      }
    }
    quadf(A, kq + 1, wB, acc, gr8);
  }
}

__device__ __forceinline__ void bias_relu(float* acc, const float* __restrict__ Bp, int c0) {
  float bv[8];
  *(float4*)&bv[0] = *(const float4*)&Bp[c0];
  *(float4*)&bv[4] = *(const float4*)&Bp[c0 + 4];
  #pragma unroll
  for (int rr = 0; rr < 8; ++rr)
    #pragma unroll
    for (int c = 0; c < 8; ++c)
      acc[rr * 8 + c] = fmaxf(acc[rr * 8 + c] + bv[c], 0.f);
}

// LayerNorm, centered two-pass (reference formula shape) — identical math to r8's ln64g;
// P36 = LDS scratch with row stride 36 (aliased into A rows 0..2).
__device__ __forceinline__ void ln64g(float* acc, float* P36,
                                      const float* __restrict__ gg,
                                      const float* __restrict__ bb,
                                      int l, int gr8, int c0) {
  const int ls = l & 31;
  float mu[8];
  // ---- pass 1: mean ----
  #pragma unroll
  for (int rr = 0; rr < 8; ++rr) {
    const float* a = &acc[rr * 8];
    P36[(gr8 + rr) * 36 + ls] =
        (((a[0] + a[1]) + (a[2] + a[3])) + ((a[4] + a[5]) + (a[6] + a[7])));
  }
  __syncthreads();
  if (l < 16) {
    float q[8];
    #pragma unroll
    for (int j = 0; j < 8; ++j) {
      const float4 u = *(const float4*)&P36[l * 36 + 4 * j];
      q[j] = (u.x + u.y) + (u.z + u.w);
    }
    const float s = ((q[0] + q[1]) + (q[2] + q[3])) + ((q[4] + q[5]) + (q[6] + q[7]));
    P36[l * 36 + 32] = s * (1.f / 256.f);
  }
  __syncthreads();
  #pragma unroll
  for (int rr = 0; rr < 8; ++rr) mu[rr] = P36[(gr8 + rr) * 36 + 32];   // broadcast
  __syncthreads();
  // ---- pass 2: centered variance ----
  #pragma unroll
  for (int rr = 0; rr < 8; ++rr) {
    const float* a = &acc[rr * 8];
    const float m = mu[rr];
    const float d0 = a[0] - m, d1 = a[1] - m, d2 = a[2] - m, d3 = a[3] - m;
    const float d4 = a[4] - m, d5 = a[5] - m, d6 = a[6] - m, d7 = a[7] - m;
    float s = d0 * d0;
    s = fmaf(d1, d1, s); s = fmaf(d2, d2, s); s = fmaf(d3, d3, s);
    s = fmaf(d4, d4, s); s = fmaf(d5, d5, s); s = fmaf(d6, d6, s); s = fmaf(d7, d7, s);
    P36[(gr8 + rr) * 36 + ls] = s;
  }
  __syncthreads();
  if (l < 16) {
    float q[8];
    #pragma unroll
    for (int j = 0; j < 8; ++j) {
      const float4 u = *(const float4*)&P36[l * 36 + 4 * j];
      q[j] = (u.x + u.y) + (u.z + u.w);
    }
    const float s2 = ((q[0] + q[1]) + (q[2] + q[3])) + ((q[4] + q[5]) + (q[6] + q[7]));
    P36[l * 36 + 32] = 1.f / sqrtf(s2 * (1.f / 256.f) + 1e-5f);
  }
  __syncthreads();
  // ---- normalize in registers: ((x-mu)*rs)*g + b ----
  float gv[8], bv[8];
  *(float4*)&gv[0] = *(const float4*)&gg[c0];
  *(float4*)&gv[4] = *(const float4*)&gg[c0 + 4];
  *(float4*)&bv[0] = *(const float4*)&bb[c0];
  *(float4*)&bv[4] = *(const float4*)&bb[c0 + 4];
  #pragma unroll
  for (int rr = 0; rr < 8; ++rr) {
    const float rs = P36[(gr8 + rr) * 36 + 32];
    const float m = mu[rr];
    #pragma unroll
    for (int c = 0; c < 8; ++c)
      acc[rr * 8 + c] = ((acc[rr * 8 + c] - m) * rs) * gv[c] + bv[c];
  }
}

__device__ __forceinline__ void storeA64g(float (*A)[256], const float* acc, int gr8, int c0) {
  #pragma unroll
  for (int rr = 0; rr < 8; ++rr) {
    *(float4*)&A[gr8 + rr][c0] =
        make_float4(acc[rr * 8], acc[rr * 8 + 1], acc[rr * 8 + 2], acc[rr * 8 + 3]);
    *(float4*)&A[gr8 + rr][c0 + 4] =
        make_float4(acc[rr * 8 + 4], acc[rr * 8 + 5], acc[rr * 8 + 6], acc[rr * 8 + 7]);
  }
}

// ==================== fused MLP kernel ====================
// blocks 0..31: decoder-table path (16 codebook rows each, 512 total)
// blocks 32..16415: encoder path (16 x-rows each)
__global__ __launch_bounds__(64, 2) void k_mlp(
    const float* __restrict__ x, const float* __restrict__ w0, const float* __restrict__ b0,
    const float* __restrict__ wt1, const float* __restrict__ wt2, const float* __restrict__ bh,
    const float* __restrict__ lng, const float* __restrict__ lnb,
    const float* __restrict__ wtout, const float* __restrict__ bout, float* __restrict__ z,
    const float* __restrict__ cb, const float* __restrict__ wt0d, const float* __restrict__ db0,
    const float* __restrict__ wtd1, const float* __restrict__ wtd2, const float* __restrict__ dbh,
    const float* __restrict__ dlng, const float* __restrict__ dlnb,
    const float* __restrict__ dwout, const float* __restrict__ dbout,
    float* __restrict__ table, float* __restrict__ ne) {
  __shared__ float A[16][256];
  float* Pa = &A[0][0];
  const int l = threadIdx.x;
  const int gr8 = (l >> 5) * 8;
  const int c0 = (l & 31) * 8;
  float acc[64];

  if (blockIdx.x >= 32) {
    // ================= encoder =================
    const size_t rbase = (size_t)(blockIdx.x - 32) * 16;
    { // layer 0: 3 -> 256, 8 rows x 8 cols per lane
      float wv[24], bv[8];
      #pragma unroll
      for (int i = 0; i < 6; ++i) *(float4*)&wv[i * 4] = *(const float4*)&w0[c0 * 3 + i * 4];
      *(float4*)&bv[0] = *(const float4*)&b0[c0];
      *(float4*)&bv[4] = *(const float4*)&b0[c0 + 4];
      #pragma unroll
      for (int rr = 0; rr < 8; ++rr) {
        const size_t r3 = (rbase + gr8 + rr) * 3;
        const float x0 = x[r3], x1 = x[r3 + 1], x2 = x[r3 + 2];
        #pragma unroll
        for (int c = 0; c < 8; ++c) {
          const float s = fmaf(wv[c * 3 + 2], x2, fmaf(wv[c * 3 + 1], x1, wv[c * 3] * x0));
          acc[rr * 8 + c] = fmaxf(s + bv[c], 0.f);
        }
      }
    }
    ln64g(acc, Pa, lng, lnb, l, gr8, c0);
    storeA64g(A, acc, gr8, c0);
    __syncthreads();

    gemm256<64>(A, wt1, acc, gr8, c0);
    bias_relu(acc, bh, c0);
    ln64g(acc, Pa, lng + 256, lnb + 256, l, gr8, c0);
    __syncthreads();
    storeA64g(A, acc, gr8, c0);
    __syncthreads();

    gemm256<64>(A, wt2, acc, gr8, c0);
    bias_relu(acc, bh + 256, c0);
    ln64g(acc, Pa, lng + 512, lnb + 512, l, gr8, c0);
    __syncthreads();
    storeA64g(A, acc, gr8, c0);
    __syncthreads();

    { // out layer 256 -> 64: 8 rows x 2 cols per lane
      const int c0o = (l & 31) * 2;
      float o[16];
      #pragma unroll
      for (int i = 0; i < 16; ++i) o[i] = 0.f;
      #pragma unroll 1
      for (int kq = 0; kq < 64; ++kq) {
        float4 a[8];
        #pragma unroll
        for (int i = 0; i < 8; ++i) a[i] = *(const float4*)&A[gr8 + i][kq * 4];
        #pragma unroll
        for (int kk = 0; kk < 4; ++kk) {
          const float2 wv = *(const float2*)&wtout[(size_t)(kq * 4 + kk) * 64 + c0o];
          #pragma unroll
          for (int i = 0; i < 8; ++i) {
            const float av = kk == 0 ? a[i].x : kk == 1 ? a[i].y : kk == 2 ? a[i].z : a[i].w;
            o[i * 2]     = fmaf(av, wv.x, o[i * 2]);
            o[i * 2 + 1] = fmaf(av, wv.y, o[i * 2 + 1]);
          }
        }
      }
      const float2 bb = *(const float2*)&bout[c0o];
      #pragma unroll
      for (int rr = 0; rr < 8; ++rr) {
        float2 st;
        st.x = o[rr * 2] + bb.x;
        st.y = o[rr * 2 + 1] + bb.y;
        *(float2*)&z[(rbase + gr8 + rr) * 64 + c0o] = st;
      }
    }
  } else {
    // ================= decoder table (dec(codebook)) =================
    const int cbase = blockIdx.x * 16;
    if (l < 16) { // ||e||^2, exact sequential chain (bit-identical to prior rounds)
      float s = 0.f;
      #pragma unroll 8
      for (int k = 0; k < 64; ++k) {
        const float v = cb[(size_t)(cbase + l) * 64 + k];
        s = fmaf(v, v, s);
      }
      ne[cbase + l] = s;
    }
    { // stage 16 codebook rows into A[r][0..63]
      const float4* cbf = (const float4*)(cb + (size_t)cbase * 64);
      const int r = l >> 2, q = l & 3;
      #pragma unroll
      for (int i = 0; i < 4; ++i)
        *(float4*)&A[r][q * 16 + i * 4] = cbf[r * 16 + q * 4 + i];
    }
    __syncthreads();

    gemm256<16>(A, wt0d, acc, gr8, c0);      // dec layer 0: 64 -> 256
    bias_relu(acc, db0, c0);
    ln64g(acc, Pa, dlng, dlnb, l, gr8, c0);
    __syncthreads();
    storeA64g(A, acc, gr8, c0);
    __syncthreads();

    gemm256<64>(A, wtd1, acc, gr8, c0);
    bias_relu(acc, dbh, c0);
    ln64g(acc, Pa, dlng + 256, dlnb + 256, l, gr8, c0);
    __syncthreads();
    storeA64g(A, acc, gr8, c0);
    __syncthreads();

    gemm256<64>(A, wtd2, acc, gr8, c0);
    bias_relu(acc, dbh + 256, c0);
    ln64g(acc, Pa, dlng + 512, dlnb + 512, l, gr8, c0);
    __syncthreads();
    storeA64g(A, acc, gr8, c0);
    __syncthreads();

    if (l < 16) { // final 256 -> 3, lane = row
      #pragma unroll
      for (int j = 0; j < 3; ++j) {
        float s = 0.f;
        #pragma unroll 4
        for (int kq = 0; kq < 64; ++kq) {
          const float4 w = *(const float4*)&dwout[j * 256 + kq * 4];
          const float4 a = *(const float4*)&A[l][kq * 4];
          s = fma4(w, a, s);
        }
        table[(cbase + l) * 3 + j] = s + dbout[j];
      }
    }
  }
}

// ---------------- weight transposes (enc + dec): WT[k][j] = W[j][k] ----------------
__global__ __launch_bounds__(256) void k_wt(
    const float* __restrict__ wh, const float* __restrict__ wout,
    const float* __restrict__ dwh, const float* __restrict__ dw0,
    float* __restrict__ wt1, float* __restrict__ wt2, float* __restrict__ wtout,
    float* __restrict__ wtd1, float* __restrict__ wtd2, float* __restrict__ wt0d) {
  const int b = blockIdx.x, t = threadIdx.x;
  if (b < 256) {
    wt1[b * 256 + t] = wh[t * 256 + b];
  } else if (b < 512) {
    const int k = b - 256;
    wt2[k * 256 + t] = wh[65536 + t * 256 + k];
  } else if (b < 576) {
    const int k = (b - 512) * 4 + (t >> 6);
    const int j = t & 63;
    wtout[k * 64 + j] = wout[j * 256 + k];
  } else if (b < 832) {
    const int k = b - 576;
    wtd1[k * 256 + t] = dwh[t * 256 + k];
  } else if (b < 1088) {
    const int k = b - 832;
    wtd2[k * 256 + t] = dwh[65536 + t * 256 + k];
  } else {
    const int k = b - 1088;               // 0..63
    wt0d[k * 256 + t] = dw0[t * 64 + k];
  }
}

// ---- VQ: z (in zq_io) -> argmin, quantized in-place, recon gather, partials ----
// 2 codes per iteration: per-code dot math (2 chains, da/db) is bit-identical to the
// passing r10 version; only cross-code instruction scheduling changes. Compare order
// (c before c+1, strict <) preserves first-min semantics exactly.
__global__ __launch_bounds__(256) void k_vq(
    float* __restrict__ zq_io, const float* __restrict__ cb,
    const float* __restrict__ ne, const float* __restrict__ table,
    const float* __restrict__ x, float* __restrict__ recon,
    float* __restrict__ psr, float* __restrict__ psv) {
  __shared__ float red[256];
  const int t = threadIdx.x;
  const int row = blockIdx.x * 256 + t;
  float4 zf[16];
  {
    const float4* zp = (const float4*)(zq_io + (size_t)row * 64);
    #pragma unroll
    for (int q = 0; q < 16; ++q) zf[q] = zp[q];
  }
  float nz = 0.f;
  #pragma unroll
  for (int q = 0; q < 16; ++q) {
    nz = fmaf(zf[q].x, zf[q].x, nz);
    nz = fmaf(zf[q].y, zf[q].y, nz);
    nz = fmaf(zf[q].z, zf[q].z, nz);
    nz = fmaf(zf[q].w, zf[q].w, nz);
  }
  float dmin = INFINITY; int imin = 0;
  const float4* cbv = (const float4*)cb;
  #pragma unroll 1
  for (int c = 0; c < 512; c += 2) {
    float da = 0.f, db = 0.f;      // code c   (chain structure identical to r10)
    float dc = 0.f, dd = 0.f;      // code c+1 (chain structure identical to r10)
    #pragma unroll
    for (int q = 0; q < 16; q += 2) {
      const float4 ea = cbv[c * 16 + q];
      const float4 eb = cbv[c * 16 + q + 1];
      const float4 ec = cbv[(c + 1) * 16 + q];
      const float4 ed = cbv[(c + 1) * 16 + q + 1];
      da = fmaf(ea.x, zf[q].x, da);
      da = fmaf(ea.y, zf[q].y, da);
      da = fmaf(ea.z, zf[q].z, da);
      da = fmaf(ea.w, zf[q].w, da);
      db = fmaf(eb.x, zf[q + 1].x, db);
      db = fmaf(eb.y, zf[q + 1].y, db);
      db = fmaf(eb.z, zf[q + 1].z, db);
      db = fmaf(eb.w, zf[q + 1].w, db);
      dc = fmaf(ec.x, zf[q].x, dc);
      dc = fmaf(ec.y, zf[q].y, dc);
      dc = fmaf(ec.z, zf[q].z, dc);
      dc = fmaf(ec.w, zf[q].w, dc);
      dd = fmaf(ed.x, zf[q + 1].x, dd);
      dd = fmaf(ed.y, zf[q + 1].y, dd);
      dd = fmaf(ed.z, zf[q + 1].z, dd);
      dd = fmaf(ed.w, zf[q + 1].w, dd);
    }
    const float d0 = (nz + ne[c]) - 2.f * (da + db);
    const float d1 = (nz + ne[c + 1]) - 2.f * (dc + dd);
    if (d0 < dmin) { dmin = d0; imin = c; }
    if (d1 < dmin) { dmin = d1; imin = c + 1; }
  }
  float sv = 0.f;
  {
    const float4* eq = (const float4*)(cb + imin * 64);
    float4* qo = (float4*)(zq_io + (size_t)row * 64);
    #pragma unroll
    for (int q = 0; q < 16; ++q) {
      const float4 e = eq[q];
      const float4 zz = zf[q];
      const float ax = e.x - zz.x, ay = e.y - zz.y, az = e.z - zz.z, aw = e.w - zz.w;
      sv = fmaf(ax, ax, sv); sv = fmaf(ay, ay, sv);
      sv = fmaf(az, az, sv); sv = fmaf(aw, aw, sv);
      float4 st;
      st.x = zz.x + ax; st.y = zz.y + ay; st.z = zz.z + az; st.w = zz.w + aw;
      qo[q] = st;
    }
  }
  const float r0 = table[imin * 3], r1 = table[imin * 3 + 1], r2 = table[imin * 3 + 2];
  recon[row * 3] = r0; recon[row * 3 + 1] = r1; recon[row * 3 + 2] = r2;
  const float e0 = r0 - x[row * 3], e1 = r1 - x[row * 3 + 1], e2 = r2 - x[row * 3 + 2];
  const float sr = fmaf(e2, e2, fmaf(e1, e1, e0 * e0));
  red[t] = sr; __syncthreads();
  #pragma unroll
  for (int o = 128; o > 0; o >>= 1) { if (t < o) red[t] += red[t + o]; __syncthreads(); }
  if (t == 0) psr[blockIdx.x] = red[0];
  __syncthreads();
  red[t] = sv; __syncthreads();
  #pragma unroll
  for (int o = 128; o > 0; o >>= 1) { if (t < o) red[t] += red[t + o]; __syncthreads(); }
  if (t == 0) psv[blockIdx.x] = red[0];
}

// ---------------- final scalar loss ----------------
__global__ __launch_bounds__(256) void k_loss(
    const float* __restrict__ psr, const float* __restrict__ psv,
    float* __restrict__ out) {
  __shared__ float ra[256], rb[256];
  const int t = threadIdx.x;
  const float sr = ((psr[t] + psr[t + 256]) + psr[t + 512]) + psr[t + 768];
  const float sv = ((psv[t] + psv[t + 256]) + psv[t + 512]) + psv[t + 768];
  ra[t] = sr; rb[t] = sv;
  __syncthreads();
  #pragma unroll
  for (int o = 128; o > 0; o >>= 1) {
    if (t < o) { ra[t] += ra[t + o]; rb[t] += rb[t + o]; }
    __syncthreads();
  }
  if (t == 0) {
    const float mr = ra[0] / 786432.f;
    const float mv = rb[0] * (1.f / 16777216.f);
    const float vq = 0.25f * mv + mv;
    out[0] = mr + vq;
  }
}

extern "C" void kernel_launch(void* const* d_in, const int* in_sizes, int n_in,
                              void* d_out, int out_size, void* d_ws, size_t ws_size,
                              hipStream_t stream) {
  const float* x        = (const float*)d_in[0];
  const float* enc_w0   = (const float*)d_in[1];
  const float* enc_b0   = (const float*)d_in[2];
  const float* enc_wh   = (const float*)d_in[3];
  const float* enc_bh   = (const float*)d_in[4];
  const float* enc_lng  = (const float*)d_in[5];
  const float* enc_lnb  = (const float*)d_in[6];
  const float* enc_wout = (const float*)d_in[7];
  const float* enc_bout = (const float*)d_in[8];
  const float* cb       = (const float*)d_in[9];
  const float* dec_w0   = (const float*)d_in[10];
  const float* dec_b0   = (const float*)d_in[11];
  const float* dec_wh   = (const float*)d_in[12];
  const float* dec_bh   = (const float*)d_in[13];
  const float* dec_lng  = (const float*)d_in[14];
  const float* dec_lnb  = (const float*)d_in[15];
  const float* dec_wout = (const float*)d_in[16];
  const float* dec_bout = (const float*)d_in[17];

  float* out   = (float*)d_out;
  float* recon = out;                       // [N,3]
  float* qbuf  = out + 786432;              // [N,64]: z, then quantized in place
  float* lossp = out + 786432 + 16777216;   // scalar

  // Transposed weights live in the recon region (written before k_mlp reads them,
  // fully overwritten by k_vq afterwards -> deterministic across replays).
  float* wt1   = out;                       // 65536
  float* wt2   = out + 65536;               // 65536
  float* wtout = out + 131072;              // 16384
  float* wtd1  = out + 147456;              // 65536
  float* wtd2  = out + 212992;              // 65536
  float* wt0d  = out + 278528;              // 16384  (total 294912 < 786432)

  float* ws    = (float*)d_ws;
  float* ne    = ws;          // 512
  float* table = ws + 512;    // 512*3
  float* psr   = ws + 2048;   // 1024
  float* psv   = ws + 3072;   // 1024

  k_wt<<<1152, 256, 0, stream>>>(enc_wh, enc_wout, dec_wh, dec_w0,
                                 wt1, wt2, wtout, wtd1, wtd2, wt0d);
  k_mlp<<<16416, 64, 0, stream>>>(x, enc_w0, enc_b0, wt1, wt2, enc_bh,
                                  enc_lng, enc_lnb, wtout, enc_bout, qbuf,
                                  cb, wt0d, dec_b0, wtd1, wtd2, dec_bh,
                                  dec_lng, dec_lnb, dec_wout, dec_bout,
                                  table, ne);
  k_vq<<<1024, 256, 0, stream>>>(qbuf, cb, ne, table, x, recon, psr, psv);
  k_loss<<<1, 256, 0, stream>>>(psr, psv, lossp);
}

// Round 14
// 1303.948 us; speedup vs baseline: 1.2002x; 1.2002x over previous
//
#include <hip/hip_runtime.h>
#include <math.h>

__device__ __forceinline__ float fma4(float4 w, float4 a, float acc) {
  return fmaf(w.w, a.w, fmaf(w.z, a.z, fmaf(w.y, a.y, fmaf(w.x, a.x, acc))));
}

// ==================== shared device helpers (1 wave, 16 rows, 8 cols/lane) ====================
// Lane group gr8 = (l>>5)*8 owns rows gr8..gr8+7; lane owns cols c0..c0+7 (c0=(l&31)*8).
// A[16][256] = 16 KB. LN scratch P aliased into A (rows 0..2): row stride 36, slots 0..31
// partials + slot 32 stat. Safe because every P write happens after the A tile has been
// fully consumed into registers (single in-order wave) and before storeA rewrites A.

// 256-FMA quad step: 8 rows x 8 cols, k-quad kq (A-read is 2-address broadcast).
__device__ __forceinline__ void quadf(const float (*A)[256], int kq, const float4* wbuf,
                                      float* acc, int gr8) {
  float4 a_[8];
  #pragma unroll
  for (int i = 0; i < 8; ++i) a_[i] = *(const float4*)&A[gr8 + i][kq * 4];
  #pragma unroll
  for (int kk = 0; kk < 4; ++kk) {
    const float4 wlo = wbuf[kk * 2], whi = wbuf[kk * 2 + 1];
    #pragma unroll
    for (int i = 0; i < 8; ++i) {
      const float av = kk == 0 ? a_[i].x : kk == 1 ? a_[i].y : kk == 2 ? a_[i].z : a_[i].w;
      acc[i * 8 + 0] = fmaf(av, wlo.x, acc[i * 8 + 0]);
      acc[i * 8 + 1] = fmaf(av, wlo.y, acc[i * 8 + 1]);
      acc[i * 8 + 2] = fmaf(av, wlo.z, acc[i * 8 + 2]);
      acc[i * 8 + 3] = fmaf(av, wlo.w, acc[i * 8 + 3]);
      acc[i * 8 + 4] = fmaf(av, whi.x, acc[i * 8 + 4]);
      acc[i * 8 + 5] = fmaf(av, whi.y, acc[i * 8 + 5]);
      acc[i * 8 + 6] = fmaf(av, whi.z, acc[i * 8 + 6]);
      acc[i * 8 + 7] = fmaf(av, whi.w, acc[i * 8 + 7]);
    }
  }
}

// GEMM: acc[8r x 8c] = A[16][4*NKQ] @ WT, W double-buffered (identical order to r8).
template <int NKQ>
__device__ __forceinline__ void gemm256(const float (*A)[256], const float* __restrict__ WT,
                                        float* acc, int gr8, int c0) {
  #pragma unroll
  for (int i = 0; i < 64; ++i) acc[i] = 0.f;
  float4 wA[8], wB[8];
  #pragma unroll
  for (int kk = 0; kk < 4; ++kk) {
    wA[kk * 2]     = *(const float4*)&WT[(size_t)kk * 256 + c0];
    wA[kk * 2 + 1] = *(const float4*)&WT[(size_t)kk * 256 + c0 + 4];
  }
  #pragma unroll 1
  for (int kq = 0; kq < NKQ; kq += 2) {
    #pragma unroll
    for (int kk = 0; kk < 4; ++kk) {
      wB[kk * 2]     = *(const float4*)&WT[(size_t)((kq + 1) * 4 + kk) * 256 + c0];
      wB[kk * 2 + 1] = *(const float4*)&WT[(size_t)((kq + 1) * 4 + kk) * 256 + c0 + 4];
    }
    quadf(A, kq, wA, acc, gr8);
    if (kq + 2 < NKQ) {
      #pragma unroll
      for (int kk = 0; kk < 4; ++kk) {
        wA[kk * 2]     = *(const float4*)&WT[(size_t)((kq + 2) * 4 + kk) * 256 + c0];
        wA[kk * 2 + 1] = *(const float4*)&WT[(size_t)((kq + 2) * 4 + kk) * 256 + c0 + 4];
      }
    }
    quadf(A, kq + 1, wB, acc, gr8);
  }
}

__device__ __forceinline__ void bias_relu(float* acc, const float* __restrict__ Bp, int c0) {
  float bv[8];
  *(float4*)&bv[0] = *(const float4*)&Bp[c0];
  *(float4*)&bv[4] = *(const float4*)&Bp[c0 + 4];
  #pragma unroll
  for (int rr = 0; rr < 8; ++rr)
    #pragma unroll
    for (int c = 0; c < 8; ++c)
      acc[rr * 8 + c] = fmaxf(acc[rr * 8 + c] + bv[c], 0.f);
}

// LayerNorm, centered two-pass (reference formula shape) — identical math to r8's ln64g;
// P36 = LDS scratch with row stride 36 (aliased into A rows 0..2).
__device__ __forceinline__ void ln64g(float* acc, float* P36,
                                      const float* __restrict__ gg,
                                      const float* __restrict__ bb,
                                      int l, int gr8, int c0) {
  const int ls = l & 31;
  float mu[8];
  // ---- pass 1: mean ----
  #pragma unroll
  for (int rr = 0; rr < 8; ++rr) {
    const float* a = &acc[rr * 8];
    P36[(gr8 + rr) * 36 + ls] =
        (((a[0] + a[1]) + (a[2] + a[3])) + ((a[4] + a[5]) + (a[6] + a[7])));
  }
  __syncthreads();
  if (l < 16) {
    float q[8];
    #pragma unroll
    for (int j = 0; j < 8; ++j) {
      const float4 u = *(const float4*)&P36[l * 36 + 4 * j];
      q[j] = (u.x + u.y) + (u.z + u.w);
    }
    const float s = ((q[0] + q[1]) + (q[2] + q[3])) + ((q[4] + q[5]) + (q[6] + q[7]));
    P36[l * 36 + 32] = s * (1.f / 256.f);
  }
  __syncthreads();
  #pragma unroll
  for (int rr = 0; rr < 8; ++rr) mu[rr] = P36[(gr8 + rr) * 36 + 32];   // broadcast
  __syncthreads();
  // ---- pass 2: centered variance ----
  #pragma unroll
  for (int rr = 0; rr < 8; ++rr) {
    const float* a = &acc[rr * 8];
    const float m = mu[rr];
    const float d0 = a[0] - m, d1 = a[1] - m, d2 = a[2] - m, d3 = a[3] - m;
    const float d4 = a[4] - m, d5 = a[5] - m, d6 = a[6] - m, d7 = a[7] - m;
    float s = d0 * d0;
    s = fmaf(d1, d1, s); s = fmaf(d2, d2, s); s = fmaf(d3, d3, s);
    s = fmaf(d4, d4, s); s = fmaf(d5, d5, s); s = fmaf(d6, d6, s); s = fmaf(d7, d7, s);
    P36[(gr8 + rr) * 36 + ls] = s;
  }
  __syncthreads();
  if (l < 16) {
    float q[8];
    #pragma unroll
    for (int j = 0; j < 8; ++j) {
      const float4 u = *(const float4*)&P36[l * 36 + 4 * j];
      q[j] = (u.x + u.y) + (u.z + u.w);
    }
    const float s2 = ((q[0] + q[1]) + (q[2] + q[3])) + ((q[4] + q[5]) + (q[6] + q[7]));
    P36[l * 36 + 32] = 1.f / sqrtf(s2 * (1.f / 256.f) + 1e-5f);
  }
  __syncthreads();
  // ---- normalize in registers: ((x-mu)*rs)*g + b ----
  float gv[8], bv[8];
  *(float4*)&gv[0] = *(const float4*)&gg[c0];
  *(float4*)&gv[4] = *(const float4*)&gg[c0 + 4];
  *(float4*)&bv[0] = *(const float4*)&bb[c0];
  *(float4*)&bv[4] = *(const float4*)&bb[c0 + 4];
  #pragma unroll
  for (int rr = 0; rr < 8; ++rr) {
    const float rs = P36[(gr8 + rr) * 36 + 32];
    const float m = mu[rr];
    #pragma unroll
    for (int c = 0; c < 8; ++c)
      acc[rr * 8 + c] = ((acc[rr * 8 + c] - m) * rs) * gv[c] + bv[c];
  }
}

__device__ __forceinline__ void storeA64g(float (*A)[256], const float* acc, int gr8, int c0) {
  #pragma unroll
  for (int rr = 0; rr < 8; ++rr) {
    *(float4*)&A[gr8 + rr][c0] =
        make_float4(acc[rr * 8], acc[rr * 8 + 1], acc[rr * 8 + 2], acc[rr * 8 + 3]);
    *(float4*)&A[gr8 + rr][c0 + 4] =
        make_float4(acc[rr * 8 + 4], acc[rr * 8 + 5], acc[rr * 8 + 6], acc[rr * 8 + 7]);
  }
}

// ==================== fused MLP kernel ====================
// blocks 0..31: decoder-table path (16 codebook rows each, 512 total)
// blocks 32..16415: encoder path (16 x-rows each)
__global__ __launch_bounds__(64, 2) void k_mlp(
    const float* __restrict__ x, const float* __restrict__ w0, const float* __restrict__ b0,
    const float* __restrict__ wt1, const float* __restrict__ wt2, const float* __restrict__ bh,
    const float* __restrict__ lng, const float* __restrict__ lnb,
    const float* __restrict__ wtout, const float* __restrict__ bout, float* __restrict__ z,
    const float* __restrict__ cb, const float* __restrict__ wt0d, const float* __restrict__ db0,
    const float* __restrict__ wtd1, const float* __restrict__ wtd2, const float* __restrict__ dbh,
    const float* __restrict__ dlng, const float* __restrict__ dlnb,
    const float* __restrict__ dwout, const float* __restrict__ dbout,
    float* __restrict__ table, float* __restrict__ ne) {
  __shared__ float A[16][256];
  float* Pa = &A[0][0];
  const int l = threadIdx.x;
  const int gr8 = (l >> 5) * 8;
  const int c0 = (l & 31) * 8;
  float acc[64];

  if (blockIdx.x >= 32) {
    // ================= encoder =================
    const size_t rbase = (size_t)(blockIdx.x - 32) * 16;
    { // layer 0: 3 -> 256, 8 rows x 8 cols per lane
      float wv[24], bv[8];
      #pragma unroll
      for (int i = 0; i < 6; ++i) *(float4*)&wv[i * 4] = *(const float4*)&w0[c0 * 3 + i * 4];
      *(float4*)&bv[0] = *(const float4*)&b0[c0];
      *(float4*)&bv[4] = *(const float4*)&b0[c0 + 4];
      #pragma unroll
      for (int rr = 0; rr < 8; ++rr) {
        const size_t r3 = (rbase + gr8 + rr) * 3;
        const float x0 = x[r3], x1 = x[r3 + 1], x2 = x[r3 + 2];
        #pragma unroll
        for (int c = 0; c < 8; ++c) {
          const float s = fmaf(wv[c * 3 + 2], x2, fmaf(wv[c * 3 + 1], x1, wv[c * 3] * x0));
          acc[rr * 8 + c] = fmaxf(s + bv[c], 0.f);
        }
      }
    }
    ln64g(acc, Pa, lng, lnb, l, gr8, c0);
    storeA64g(A, acc, gr8, c0);
    __syncthreads();

    gemm256<64>(A, wt1, acc, gr8, c0);
    bias_relu(acc, bh, c0);
    ln64g(acc, Pa, lng + 256, lnb + 256, l, gr8, c0);
    __syncthreads();
    storeA64g(A, acc, gr8, c0);
    __syncthreads();

    gemm256<64>(A, wt2, acc, gr8, c0);
    bias_relu(acc, bh + 256, c0);
    ln64g(acc, Pa, lng + 512, lnb + 512, l, gr8, c0);
    __syncthreads();
    storeA64g(A, acc, gr8, c0);
    __syncthreads();

    { // out layer 256 -> 64: 8 rows x 2 cols per lane
      const int c0o = (l & 31) * 2;
      float o[16];
      #pragma unroll
      for (int i = 0; i < 16; ++i) o[i] = 0.f;
      #pragma unroll 1
      for (int kq = 0; kq < 64; ++kq) {
        float4 a[8];
        #pragma unroll
        for (int i = 0; i < 8; ++i) a[i] = *(const float4*)&A[gr8 + i][kq * 4];
        #pragma unroll
        for (int kk = 0; kk < 4; ++kk) {
          const float2 wv = *(const float2*)&wtout[(size_t)(kq * 4 + kk) * 64 + c0o];
          #pragma unroll
          for (int i = 0; i < 8; ++i) {
            const float av = kk == 0 ? a[i].x : kk == 1 ? a[i].y : kk == 2 ? a[i].z : a[i].w;
            o[i * 2]     = fmaf(av, wv.x, o[i * 2]);
            o[i * 2 + 1] = fmaf(av, wv.y, o[i * 2 + 1]);
          }
        }
      }
      const float2 bb = *(const float2*)&bout[c0o];
      #pragma unroll
      for (int rr = 0; rr < 8; ++rr) {
        float2 st;
        st.x = o[rr * 2] + bb.x;
        st.y = o[rr * 2 + 1] + bb.y;
        *(float2*)&z[(rbase + gr8 + rr) * 64 + c0o] = st;
      }
    }
  } else {
    // ================= decoder table (dec(codebook)) =================
    const int cbase = blockIdx.x * 16;
    if (l < 16) { // ||e||^2, exact sequential chain (bit-identical to prior rounds)
      float s = 0.f;
      #pragma unroll 8
      for (int k = 0; k < 64; ++k) {
        const float v = cb[(size_t)(cbase + l) * 64 + k];
        s = fmaf(v, v, s);
      }
      ne[cbase + l] = s;
    }
    { // stage 16 codebook rows into A[r][0..63]
      const float4* cbf = (const float4*)(cb + (size_t)cbase * 64);
      const int r = l >> 2, q = l & 3;
      #pragma unroll
      for (int i = 0; i < 4; ++i)
        *(float4*)&A[r][q * 16 + i * 4] = cbf[r * 16 + q * 4 + i];
    }
    __syncthreads();

    gemm256<16>(A, wt0d, acc, gr8, c0);      // dec layer 0: 64 -> 256
    bias_relu(acc, db0, c0);
    ln64g(acc, Pa, dlng, dlnb, l, gr8, c0);
    __syncthreads();
    storeA64g(A, acc, gr8, c0);
    __syncthreads();

    gemm256<64>(A, wtd1, acc, gr8, c0);
    bias_relu(acc, dbh, c0);
    ln64g(acc, Pa, dlng + 256, dlnb + 256, l, gr8, c0);
    __syncthreads();
    storeA64g(A, acc, gr8, c0);
    __syncthreads();

    gemm256<64>(A, wtd2, acc, gr8, c0);
    bias_relu(acc, dbh + 256, c0);
    ln64g(acc, Pa, dlng + 512, dlnb + 512, l, gr8, c0);
    __syncthreads();
    storeA64g(A, acc, gr8, c0);
    __syncthreads();

    if (l < 16) { // final 256 -> 3, lane = row
      #pragma unroll
      for (int j = 0; j < 3; ++j) {
        float s = 0.f;
        #pragma unroll 4
        for (int kq = 0; kq < 64; ++kq) {
          const float4 w = *(const float4*)&dwout[j * 256 + kq * 4];
          const float4 a = *(const float4*)&A[l][kq * 4];
          s = fma4(w, a, s);
        }
        table[(cbase + l) * 3 + j] = s + dbout[j];
      }
    }
  }
}

// ---------------- weight transposes (enc + dec): WT[k][j] = W[j][k] ----------------
__global__ __launch_bounds__(256) void k_wt(
    const float* __restrict__ wh, const float* __restrict__ wout,
    const float* __restrict__ dwh, const float* __restrict__ dw0,
    float* __restrict__ wt1, float* __restrict__ wt2, float* __restrict__ wtout,
    float* __restrict__ wtd1, float* __restrict__ wtd2, float* __restrict__ wt0d) {
  const int b = blockIdx.x, t = threadIdx.x;
  if (b < 256) {
    wt1[b * 256 + t] = wh[t * 256 + b];
  } else if (b < 512) {
    const int k = b - 256;
    wt2[k * 256 + t] = wh[65536 + t * 256 + k];
  } else if (b < 576) {
    const int k = (b - 512) * 4 + (t >> 6);
    const int j = t & 63;
    wtout[k * 64 + j] = wout[j * 256 + k];
  } else if (b < 832) {
    const int k = b - 576;
    wtd1[k * 256 + t] = dwh[t * 256 + k];
  } else if (b < 1088) {
    const int k = b - 832;
    wtd2[k * 256 + t] = dwh[65536 + t * 256 + k];
  } else {
    const int k = b - 1088;               // 0..63
    wt0d[k * 256 + t] = dw0[t * 64 + k];
  }
}

// ---- VQ: z (in zq_io) -> argmin, quantized in-place, recon gather, partials ----
__global__ __launch_bounds__(256) void k_vq(
    float* __restrict__ zq_io, const float* __restrict__ cb,
    const float* __restrict__ ne, const float* __restrict__ table,
    const float* __restrict__ x, float* __restrict__ recon,
    float* __restrict__ psr, float* __restrict__ psv) {
  __shared__ float red[256];
  const int t = threadIdx.x;
  const int row = blockIdx.x * 256 + t;
  float4 zf[16];
  {
    const float4* zp = (const float4*)(zq_io + (size_t)row * 64);
    #pragma unroll
    for (int q = 0; q < 16; ++q) zf[q] = zp[q];
  }
  float nz = 0.f;
  #pragma unroll
  for (int q = 0; q < 16; ++q) {
    nz = fmaf(zf[q].x, zf[q].x, nz);
    nz = fmaf(zf[q].y, zf[q].y, nz);
    nz = fmaf(zf[q].z, zf[q].z, nz);
    nz = fmaf(zf[q].w, zf[q].w, nz);
  }
  float dmin = INFINITY; int imin = 0;
  const float4* cbv = (const float4*)cb;
  for (int c = 0; c < 512; ++c) {
    float da = 0.f, db = 0.f;
    #pragma unroll
    for (int q = 0; q < 16; q += 2) {
      const float4 ea = cbv[c * 16 + q];
      const float4 eb = cbv[c * 16 + q + 1];
      da = fmaf(ea.x, zf[q].x, da);
      da = fmaf(ea.y, zf[q].y, da);
      da = fmaf(ea.z, zf[q].z, da);
      da = fmaf(ea.w, zf[q].w, da);
      db = fmaf(eb.x, zf[q + 1].x, db);
      db = fmaf(eb.y, zf[q + 1].y, db);
      db = fmaf(eb.z, zf[q + 1].z, db);
      db = fmaf(eb.w, zf[q + 1].w, db);
    }
    const float dot = da + db;
    const float d = (nz + ne[c]) - 2.f * dot;
    if (d < dmin) { dmin = d; imin = c; }
  }
  float sv = 0.f;
  {
    const float4* eq = (const float4*)(cb + imin * 64);
    float4* qo = (float4*)(zq_io + (size_t)row * 64);
    #pragma unroll
    for (int q = 0; q < 16; ++q) {
      const float4 e = eq[q];
      const float4 zz = zf[q];
      const float ax = e.x - zz.x, ay = e.y - zz.y, az = e.z - zz.z, aw = e.w - zz.w;
      sv = fmaf(ax, ax, sv); sv = fmaf(ay, ay, sv);
      sv = fmaf(az, az, sv); sv = fmaf(aw, aw, sv);
      float4 st;
      st.x = zz.x + ax; st.y = zz.y + ay; st.z = zz.z + az; st.w = zz.w + aw;
      qo[q] = st;
    }
  }
  const float r0 = table[imin * 3], r1 = table[imin * 3 + 1], r2 = table[imin * 3 + 2];
  recon[row * 3] = r0; recon[row * 3 + 1] = r1; recon[row * 3 + 2] = r2;
  const float e0 = r0 - x[row * 3], e1 = r1 - x[row * 3 + 1], e2 = r2 - x[row * 3 + 2];
  const float sr = fmaf(e2, e2, fmaf(e1, e1, e0 * e0));
  red[t] = sr; __syncthreads();
  #pragma unroll
  for (int o = 128; o > 0; o >>= 1) { if (t < o) red[t] += red[t + o]; __syncthreads(); }
  if (t == 0) psr[blockIdx.x] = red[0];
  __syncthreads();
  red[t] = sv; __syncthreads();
  #pragma unroll
  for (int o = 128; o > 0; o >>= 1) { if (t < o) red[t] += red[t + o]; __syncthreads(); }
  if (t == 0) psv[blockIdx.x] = red[0];
}

// ---------------- final scalar loss ----------------
__global__ __launch_bounds__(256) void k_loss(
    const float* __restrict__ psr, const float* __restrict__ psv,
    float* __restrict__ out) {
  __shared__ float ra[256], rb[256];
  const int t = threadIdx.x;
  const float sr = ((psr[t] + psr[t + 256]) + psr[t + 512]) + psr[t + 768];
  const float sv = ((psv[t] + psv[t + 256]) + psv[t + 512]) + psv[t + 768];
  ra[t] = sr; rb[t] = sv;
  __syncthreads();
  #pragma unroll
  for (int o = 128; o > 0; o >>= 1) {
    if (t < o) { ra[t] += ra[t + o]; rb[t] += rb[t + o]; }
    __syncthreads();
  }
  if (t == 0) {
    const float mr = ra[0] / 786432.f;
    const float mv = rb[0] * (1.f / 16777216.f);
    const float vq = 0.25f * mv + mv;
    out[0] = mr + vq;
  }
}

extern "C" void kernel_launch(void* const* d_in, const int* in_sizes, int n_in,
                              void* d_out, int out_size, void* d_ws, size_t ws_size,
                              hipStream_t stream) {
  const float* x        = (const float*)d_in[0];
  const float* enc_w0   = (const float*)d_in[1];
  const float* enc_b0   = (const float*)d_in[2];
  const float* enc_wh   = (const float*)d_in[3];
  const float* enc_bh   = (const float*)d_in[4];
  const float* enc_lng  = (const float*)d_in[5];
  const float* enc_lnb  = (const float*)d_in[6];
  const float* enc_wout = (const float*)d_in[7];
  const float* enc_bout = (const float*)d_in[8];
  const float* cb       = (const float*)d_in[9];
  const float* dec_w0   = (const float*)d_in[10];
  const float* dec_b0   = (const float*)d_in[11];
  const float* dec_wh   = (const float*)d_in[12];
  const float* dec_bh   = (const float*)d_in[13];
  const float* dec_lng  = (const float*)d_in[14];
  const float* dec_lnb  = (const float*)d_in[15];
  const float* dec_wout = (const float*)d_in[16];
  const float* dec_bout = (const float*)d_in[17];

  float* out   = (float*)d_out;
  float* recon = out;                       // [N,3]
  float* qbuf  = out + 786432;              // [N,64]: z, then quantized in place
  float* lossp = out + 786432 + 16777216;   // scalar

  // Transposed weights live in the recon region (written before k_mlp reads them,
  // fully overwritten by k_vq afterwards -> deterministic across replays).
  float* wt1   = out;                       // 65536
  float* wt2   = out + 65536;               // 65536
  float* wtout = out + 131072;              // 16384
  float* wtd1  = out + 147456;              // 65536
  float* wtd2  = out + 212992;              // 65536
  float* wt0d  = out + 278528;              // 16384  (total 294912 < 786432)

  float* ws    = (float*)d_ws;
  float* ne    = ws;          // 512
  float* table = ws + 512;    // 512*3
  float* psr   = ws + 2048;   // 1024
  float* psv   = ws + 3072;   // 1024

  k_wt<<<1152, 256, 0, stream>>>(enc_wh, enc_wout, dec_wh, dec_w0,
                                 wt1, wt2, wtout, wtd1, wtd2, wt0d);
  k_mlp<<<16416, 64, 0, stream>>>(x, enc_w0, enc_b0, wt1, wt2, enc_bh,
                                  enc_lng, enc_lnb, wtout, enc_bout, qbuf,
                                  cb, wt0d, dec_b0, wtd1, wtd2, dec_bh,
                                  dec_lng, dec_lnb, dec_wout, dec_bout,
                                  table, ne);
  k_vq<<<1024, 256, 0, stream>>>(qbuf, cb, ne, table, x, recon, psr, psv);
  k_loss<<<1, 256, 0, stream>>>(psr, psv, lossp);
}